// Round 11
// baseline (226.172 us; speedup 1.0000x reference)
//
#include <hip/hip_runtime.h>
#include <stdint.h>

// Match reference numerics: no FMA contraction anywhere (discrete IoU>thres
// decisions flip on 1-ulp differences).
#pragma clang fp contract(off)

#define BATCH 32
#define NPRED 25200
#define ROWF 9
#define TOPK 1000
#define SUBS 8
#define ROWS_PER_SUB (NPRED / SUBS)   // 3150
#define SUBCAP 512
#define CONF_T 0.7f
#define IOU_T 0.45f
#define KW 16          // 1000 bits -> 16 u64 words
#define SUPROW 1024    // global sup stride per word-column
#define TKROW 1024     // tkey stride per image

typedef unsigned long long u64;
typedef unsigned int u32;

// ---- workspace layout (bytes) ----
#define WS_CAND 0                       // 256 lists x 512 u64 = 1,048,576
#define WS_TKEY (1048576)               // 32 x 1024 u64       =   262,144
#define WS_SUP  (WS_TKEY + 262144)      // 32 x 16 x 1024 u64  = 4,194,304
#define WS_FLAGS (WS_SUP + 4194304)     // 32 x 16 u32         =     2,048

// Session notes baked in:
//  - R8: grid-wide cooperative grid.sync costs ~60+ us/sync -> per-IMAGE
//    flag barriers instead (8 blocks each, co-resident since grid<=256 CUs).
//  - R9: don't concentrate LDS-broadcast loops on 1 CU/image; P3 stays
//    8 blocks/image AND moves j-broadcasts off the LDS pipe to v_readlane.
//  - R10: launch boundaries ~6 us each were ~20-30 us of the budget ->
//    single-dispatch pipeline.

__device__ __forceinline__ u64 readlane64(u64 v, int l) {
    u32 lo = __builtin_amdgcn_readlane((u32)v, (u32)l);
    u32 hi = __builtin_amdgcn_readlane((u32)(v >> 32), (u32)l);
    return ((u64)hi << 32) | lo;
}
__device__ __forceinline__ float readlanef(float v, int l) {
    return __uint_as_float(__builtin_amdgcn_readlane(__float_as_uint(v), (u32)l));
}

__global__ void zero_flags_kernel(u32* flags) {
    flags[threadIdx.x] = 0;   // 512 u32 covers 32 images x 16
}

__global__ __launch_bounds__(512) void nms_fused(const float* __restrict__ pred,
                                                 u64* __restrict__ cand_ws,
                                                 u64* __restrict__ tkey_ws,
                                                 u64* __restrict__ sup_g,
                                                 u32* __restrict__ flags,
                                                 float* __restrict__ out,
                                                 float* __restrict__ keepout) {
    __shared__ u64 arena[4096];        // 32 KB, re-carved per phase
    __shared__ u32 cnt;
    __shared__ u32 last_sh;
    __shared__ u64 keep_sh[KW];
    __shared__ u64 acc_lds;

    int bs = blockIdx.x;               // 0..255
    int b = bs & 31, s = bs >> 5;      // image b's 8 blocks share bs%8 -> same XCD (perf heuristic)
    int tid = threadIdx.x;
    int w = tid >> 6, lane = tid & 63;
    u32* fl = flags + b * 16;          // per-image flag cache line

    // ================= P1: compact + in-block bitonic sort =================
    // key = (float_bits(conf)<<32) | ~row -> desc order == (score desc, idx
    // asc), exactly jax.lax.top_k tie-breaking. ~317 valid/3150 expected;
    // SUBCAP=512 is mean+11.5 sigma. De-staged scalar loads of cols 4,5 only
    // (independent, one waitcnt). Also zeroes this image's tkey slice.
    {
        u64* skey = arena;             // 4 KB
        if (tid == 0) cnt = 0;
        skey[tid] = 0;
        if (tid < 128) tkey_ws[(size_t)b * TKROW + s * 128 + tid] = 0;
        __syncthreads();
        int r0 = s * ROWS_PER_SUB;
        const int NCH = (ROWS_PER_SUB + 511) / 512;   // 7
        float objv[NCH], clsv[NCH];
#pragma unroll
        for (int k = 0; k < NCH; ++k) {
            int r = tid + k * 512;
            if (r < ROWS_PER_SUB) {
                size_t base = ((size_t)b * NPRED + r0 + r) * ROWF;
                objv[k] = pred[base + 4];
                clsv[k] = pred[base + 5];
            }
        }
#pragma unroll
        for (int k = 0; k < NCH; ++k) {
            int r = tid + k * 512;
            if (r < ROWS_PER_SUB) {
                float conf = objv[k] * clsv[k];
                if (objv[k] > CONF_T && conf > CONF_T) {
                    int row = r0 + r;
                    u32 slot = atomicAdd(&cnt, 1u);
                    if (slot < SUBCAP)
                        skey[slot] = ((u64)__float_as_uint(conf) << 32) | (u64)(u32)(~(u32)row);
                }
            }
        }
        __syncthreads();
        for (int k = 2; k <= SUBCAP; k <<= 1) {
            for (int j = k >> 1; j > 0; j >>= 1) {
                int t = tid, p = t ^ j;
                if (p > t) {
                    u64 a = skey[t], c2 = skey[p];
                    bool desc = ((t & k) == 0);
                    if (desc ? (a < c2) : (a > c2)) { skey[t] = c2; skey[p] = a; }
                }
                __syncthreads();
            }
        }
        cand_ws[(size_t)(b * SUBS + s) * SUBCAP + tid] = skey[tid];
    }
    // ---- per-image barrier, stage 0 ----
    __threadfence();                   // every thread drains its own stores
    __syncthreads();
    if (tid == 0) {
        __hip_atomic_fetch_add(fl + 0, 1u, __ATOMIC_RELEASE, __HIP_MEMORY_SCOPE_AGENT);
        while (__hip_atomic_load(fl + 0, __ATOMIC_ACQUIRE, __HIP_MEMORY_SCOPE_AGENT) < 8u)
            __builtin_amdgcn_s_sleep(2);
    }
    __syncthreads();

    // ================= P2: rank-merge, scatter top-1000 =================
    // rank(key) = sum over all 8 sorted lists of count(> key); own list
    // contributes the key's own index (keys unique). Breadth-interleaved
    // pow2 ladder: 10 rounds x 8 independent LDS probes.
    {
        u64* lists = arena;            // 32 KB
        const u64* src = cand_ws + (size_t)b * SUBS * SUBCAP;
        for (int t = tid; t < SUBS * SUBCAP; t += 512) lists[t] = src[t];
        __syncthreads();
        u64 key = lists[(s << 9) + tid];
        if (key) {
            int lo[SUBS];
#pragma unroll
            for (int l = 0; l < SUBS; ++l) lo[l] = 0;
#pragma unroll
            for (int w2 = SUBCAP; w2 >= 1; w2 >>= 1) {
#pragma unroll
                for (int l = 0; l < SUBS; ++l) {
                    int p = lo[l] + w2;
                    if (p <= SUBCAP && lists[(l << 9) + p - 1] > key) lo[l] = p;
                }
            }
            int rank = 0;
#pragma unroll
            for (int l = 0; l < SUBS; ++l) rank += lo[l];
            if (rank < TOPK) tkey_ws[(size_t)b * TKROW + rank] = key;
        }
    }
    // ---- per-image barrier, stage 1 ----
    __threadfence();
    __syncthreads();
    if (tid == 0) {
        __hip_atomic_fetch_add(fl + 1, 1u, __ATOMIC_RELEASE, __HIP_MEMORY_SCOPE_AGENT);
        while (__hip_atomic_load(fl + 1, __ATOMIC_ACQUIRE, __HIP_MEMORY_SCOPE_AGENT) < 8u)
            __builtin_amdgcn_s_sleep(2);
    }
    __syncthreads();

    // ================= P3: suppression matrix (readlane broadcasts) ========
    // 136 upper-tri 64x64 tiles/image over 64 waves (8 blocks x 8 waves).
    // j-tile rows live in lane registers; per-j broadcast via v_readlane
    // (VALU) -- one LDS read per tile instead of 64 (R9 lesson).
    {
        float4* bx_s = (float4*)arena;              // 1024 x 16 B
        float* ar_s = (float*)(arena + 2048);       // 1024 x 4 B
        for (int t = tid; t < 1024; t += 512) {
            u64 key = tkey_ws[(size_t)b * TKROW + t];   // rows>=TOPK zeroed in P1
            float4 box = make_float4(0.f, 0.f, 0.f, 0.f);
            float ar = 0.f;
            if (key) {
                u32 r = ~(u32)key;
                const float* p = pred + ((size_t)b * NPRED + r) * ROWF;
                float x = p[0], y = p[1], wd = p[2], hh = p[3];
                box = make_float4(x - wd * 0.5f, y - hh * 0.5f, x + wd * 0.5f, y + hh * 0.5f);
                ar = (box.z - box.x) * (box.w - box.y);
            }
            bx_s[t] = box; ar_s[t] = ar;            // zero box suppresses nothing (iou=0)
        }
        __syncthreads();
        int gw = (s << 3) + w;                      // 0..63
        for (int t = gw; t < 136; t += 64) {
            int iw = 0, rem = t, c = 16;
            while (rem >= c) { rem -= c; c--; iw++; }
            int jw = iw + rem;                      // jw >= iw
            int i = (iw << 6) + lane;
            bool act = i < TOPK;
            float4 bi4 = bx_s[i];
            float ai = ar_s[i];
            float4 bja = bx_s[(jw << 6) + lane];    // this lane's j-row
            float aja = ar_s[(jw << 6) + lane];
            u64 m = 0;
            int jbase = jw << 6;
            for (int l2 = 0; l2 < 64; ++l2) {
                float bjx = readlanef(bja.x, l2);
                float bjy = readlanef(bja.y, l2);
                float bjz = readlanef(bja.z, l2);
                float bjw = readlanef(bja.w, l2);
                float aj  = readlanef(aja, l2);
                float lx = fmaxf(bi4.x, bjx);
                float ly = fmaxf(bi4.y, bjy);
                float rx = fminf(bi4.z, bjz);
                float ry = fminf(bi4.w, bjw);
                float iw2 = rx - lx; iw2 = iw2 > 0.f ? iw2 : 0.f;
                float ih = ry - ly; ih = ih > 0.f ? ih : 0.f;
                float inter = iw2 * ih;
                float den = ai + aj - inter + 1e-7f;  // ((ai+aj)-inter)+eps, ref order
                float iou = inter / den;
                if (act && (jbase + l2) > i && iou > IOU_T) m |= 1ull << l2;
            }
            if (act) sup_g[((size_t)b * KW + jw) * SUPROW + i] = m;
        }
    }
    // ---- stage 2: arrive with last-block detection (no spin) ----
    __threadfence();
    __syncthreads();
    if (tid == 0)
        last_sh = __hip_atomic_fetch_add(fl + 2, 1u, __ATOMIC_ACQ_REL, __HIP_MEMORY_SCOPE_AGENT);
    __syncthreads();
    if (last_sh != 7u) return;         // 7/8 blocks retire; last one scans

    // ================= P4: sparse greedy scan + output (last block) ========
    {
        int cA = w, cB = w + 8;        // this wave's two word-columns
        const u64* S = sup_g + (size_t)b * KW * SUPROW;

        u64 keyA = tkey_ws[(size_t)b * TKROW + tid];
        u64 keyB = tkey_ws[(size_t)b * TKROW + 512 + tid];
        u64 k0A = __ballot(keyA != 0ull);
        u64 k0B = __ballot(keyB != 0ull);
        if (lane == 0) { keep_sh[w] = k0A; keep_sh[w + 8] = k0B; }

        u64 regA[8], regB[KW];
#pragma unroll
        for (int bi = 0; bi < 8; ++bi)
            regA[bi] = S[(size_t)cA * SUPROW + (bi << 6) + lane];  // bi>=cA: garbage, gated
#pragma unroll
        for (int bi = 0; bi < KW; ++bi)
            regB[bi] = S[(size_t)cB * SUPROW + (bi << 6) + lane];  // bi>=cB: garbage, gated
        u64 diagA = S[(size_t)cA * SUPROW + (cA << 6) + lane];
        u64 diagB = S[(size_t)cB * SUPROW + (cB << 6) + lane];
        __syncthreads();
        u64 nzA = __ballot(diagA != 0ull);
        u64 nzB = __ballot(diagB != 0ull);

#pragma unroll
        for (int bi = 0; bi < KW; ++bi) {
            if (w == (bi & 7)) {
                u64 diag = (bi < 8) ? diagA : diagB;
                u64 nz = (bi < 8) ? nzA : nzB;
                u64 cur = keep_sh[bi];
                u64 active = cur & nz;            // only suppressor rows iterate
                while (active) {
                    int i = __ffsll((long long)active) - 1;
                    u64 wi = readlane64(diag, i); // row i's mask (bits>i only)
                    active &= active - 1;
                    cur &= ~wi;
                    active &= ~wi;                // suppressed rows can't suppress
                }
                if (lane == 0) { keep_sh[bi] = cur; acc_lds = cur; }
            }
            __syncthreads();
            u64 A = acc_lds;                      // accepted set of block bi
            bool accb = ((A >> lane) & 1ull) != 0;
            if (bi < 8 && cA > bi) {
                u64 myv = regA[bi];
                u64 lanes = __ballot(accb && myv != 0ull);
                if (lanes) {
                    u64 wred = 0;
                    while (lanes) {
                        int l = __ffsll((long long)lanes) - 1;
                        wred |= readlane64(myv, l);
                        lanes &= lanes - 1;
                    }
                    if (lane == 0) keep_sh[cA] &= ~wred;
                }
            }
            if (cB > bi) {
                u64 myv = regB[bi];
                u64 lanes = __ballot(accb && myv != 0ull);
                if (lanes) {
                    u64 wred = 0;
                    while (lanes) {
                        int l = __ffsll((long long)lanes) - 1;
                        wred |= readlane64(myv, l);
                        lanes &= lanes - 1;
                    }
                    if (lane == 0) keep_sh[cB] &= ~wred;
                }
            }
            __syncthreads();
        }

#pragma unroll
        for (int pass = 0; pass < 2; ++pass) {
            int row = tid + (pass << 9);
            u64 key = pass ? keyB : keyA;
            if (row < TOPK) {
                bool kp = ((keep_sh[row >> 6] >> (row & 63)) & 1ull) != 0;
                float o0 = 0.f, o1 = 0.f, o2 = 0.f, o3 = 0.f, o4 = 0.f, o6 = 0.f, o7 = 0.f, o8 = 0.f;
                if (kp) {
                    u32 r = ~(u32)key;
                    const float* p = pred + ((size_t)b * NPRED + r) * ROWF;
                    float x = p[0], y = p[1], wd = p[2], hh = p[3];
                    o0 = x - wd * 0.5f; o1 = y - hh * 0.5f;
                    o2 = x + wd * 0.5f; o3 = y + hh * 0.5f;
                    o4 = __uint_as_float((u32)(key >> 32));
                    o6 = p[6]; o7 = p[7]; o8 = p[8];
                }
                size_t ob = ((size_t)b * TOPK + row) * ROWF;
                out[ob + 0] = o0; out[ob + 1] = o1; out[ob + 2] = o2; out[ob + 3] = o3;
                out[ob + 4] = o4; out[ob + 5] = 0.f;
                out[ob + 6] = o6; out[ob + 7] = o7; out[ob + 8] = o8;
                keepout[(size_t)b * TOPK + row] = kp ? 1.0f : 0.0f;
            }
        }
    }
}

extern "C" void kernel_launch(void* const* d_in, const int* in_sizes, int n_in,
                              void* d_out, int out_size, void* d_ws, size_t ws_size,
                              hipStream_t stream) {
    const float* pred = (const float*)d_in[0];
    float* out = (float*)d_out;                         // [32,1000,9]
    float* keepout = out + (size_t)BATCH * TOPK * ROWF; // [32,1000]
    char* ws = (char*)d_ws;
    u64* cand_ws = (u64*)(ws + WS_CAND);
    u64* tkey_ws = (u64*)(ws + WS_TKEY);
    u64* sup_g = (u64*)(ws + WS_SUP);
    u32* flags = (u32*)(ws + WS_FLAGS);

    zero_flags_kernel<<<1, 512, 0, stream>>>(flags);
    nms_fused<<<BATCH * SUBS, 512, 0, stream>>>(pred, cand_ws, tkey_ws, sup_g,
                                                flags, out, keepout);
}

// Round 12
// 124.539 us; speedup vs baseline: 1.8161x; 1.8161x over previous
//
#include <hip/hip_runtime.h>
#include <stdint.h>

// Match reference numerics: no FMA contraction anywhere (discrete IoU>thres
// decisions flip on 1-ulp differences).
#pragma clang fp contract(off)

#define BATCH 32
#define NPRED 25200
#define ROWF 9
#define TOPK 1000
#define SUBS 8
#define ROWS_PER_SUB (NPRED / SUBS)   // 3150
#define SUBCAP 512
#define CONF_T 0.7f
#define IOU_T 0.45f
#define KW 16          // 1000 bits -> 16 u64 words
#define SUPROW 1024    // global sup stride per word-column
#define TKROW 1024     // bx/sa stride per image

typedef unsigned long long u64;
typedef unsigned int u32;

// ---- workspace layout (bytes) ----
#define WS_CAND 0                      // 256 lists x 512 u64 = 1,048,576
#define WS_BX   (1048576)              // 32 x 1024 float4    =   524,288
#define WS_SA   (WS_BX + 524288)       // 32 x 1024 float4    =   524,288
#define WS_SUP  (WS_SA + 524288)       // 32 x 16 x 1024 u64  = 4,194,304

// Session notes baked in:
//  - R8: grid-wide cooperative grid.sync ~60+ us/sync. Never.
//  - R11: per-image device-scope flag barriers also stall ~145 us total
//    (agent-scope fences cross the per-XCD L2 boundary). Launch boundaries
//    (~6 us) are the CHEAPEST inter-block sync on this part. 4 dispatches.
//  - R9: keep supmat at 8 blocks/image (per-CU LDS pipe limits).
//  - R12: gather top-1000 pred rows ONCE (in rank kernel), publish SoA.

__device__ __forceinline__ u64 readlane64(u64 v, int l) {
    // wave-uniform lane index -> v_readlane_b32 x2 (VALU, no LDS pipe)
    u32 lo = __builtin_amdgcn_readlane((u32)v, (u32)l);
    u32 hi = __builtin_amdgcn_readlane((u32)(v >> 32), (u32)l);
    return ((u64)hi << 32) | lo;
}

// K1: compact valid rows of one (image, sub-range) into keys, then bitonic-sort
// the 512-entry sub-list in-block (descending; zeros pad to the end).
// key = (float_bits(conf)<<32) | ~row  -> desc order == (score desc, idx asc),
// exactly jax.lax.top_k tie-breaking. ~317 valid rows per 3150 expected;
// SUBCAP=512 is mean+11.5 sigma. De-staged scalar loads of cols 4,5 only.
// Also zeroes this block's slice of bx_ws/sa_ws (0xAA-poisoned; rank_kernel
// only writes slots with rank<TOPK).
__global__ __launch_bounds__(512) void compact_sort_kernel(const float* __restrict__ pred,
                                                           u64* __restrict__ cand_ws,
                                                           float4* __restrict__ bx_ws,
                                                           float4* __restrict__ sa_ws) {
    __shared__ u64 skey[SUBCAP];          // 4096 B
    __shared__ u32 cnt;
    int bs = blockIdx.x;          // 0..255
    int b = bs >> 3, s = bs & 7;
    int tid = threadIdx.x;
    if (tid == 0) cnt = 0;
    skey[tid] = 0;
    if (tid < 128) {
        float4 z = make_float4(0.f, 0.f, 0.f, 0.f);
        bx_ws[(size_t)b * TKROW + s * 128 + tid] = z;
        sa_ws[(size_t)b * TKROW + s * 128 + tid] = z;
    }
    __syncthreads();

    // gather cols 4,5 for my rows: r = r0 + tid + k*512, k=0..6 (3150 = 6*512+78)
    int r0 = s * ROWS_PER_SUB;
    const int NCH = (ROWS_PER_SUB + 511) / 512;   // 7
    float objv[NCH], clsv[NCH];
#pragma unroll
    for (int k = 0; k < NCH; ++k) {
        int r = tid + k * 512;
        if (r < ROWS_PER_SUB) {
            size_t base = ((size_t)b * NPRED + r0 + r) * ROWF;
            objv[k] = pred[base + 4];
            clsv[k] = pred[base + 5];
        }
    }
#pragma unroll
    for (int k = 0; k < NCH; ++k) {
        int r = tid + k * 512;
        if (r < ROWS_PER_SUB) {
            float conf = objv[k] * clsv[k];
            if (objv[k] > CONF_T && conf > CONF_T) {
                int row = r0 + r;
                u32 slot = atomicAdd(&cnt, 1u);
                if (slot < SUBCAP)
                    skey[slot] = ((u64)__float_as_uint(conf) << 32) | (u64)(u32)(~(u32)row);
            }
        }
    }
    __syncthreads();
    // bitonic sort, descending, 512 elements, 512 threads (45 passes)
    for (int k = 2; k <= SUBCAP; k <<= 1) {
        for (int j = k >> 1; j > 0; j >>= 1) {
            int t = tid, p = t ^ j;
            if (p > t) {
                u64 a = skey[t], c2 = skey[p];
                bool desc = ((t & k) == 0);
                if (desc ? (a < c2) : (a > c2)) { skey[t] = c2; skey[p] = a; }
            }
            __syncthreads();
        }
    }
    cand_ws[(size_t)bs * SUBCAP + tid] = skey[tid];
}

// K2: rank + gather + publish SoA. 8 blocks per image; each block ranks its
// own sub-list's 512 keys (rank = sum over all 8 sorted lists of count(>key);
// keys unique -> ranks exact/unique). For rank < TOPK, gather the pred row
// ONCE, compute the box (identical FP expressions), and scatter
// bx_ws[b][rank] = (x1,y1,x2,y2), sa_ws[b][rank] = (score,p6,p7,p8).
__global__ __launch_bounds__(512) void rank_kernel(const float* __restrict__ pred,
                                                   const u64* __restrict__ cand_ws,
                                                   float4* __restrict__ bx_ws,
                                                   float4* __restrict__ sa_ws) {
    __shared__ u64 lists[SUBS * SUBCAP];   // 32 KB
    int bs = blockIdx.x;          // 0..255
    int b = bs >> 3, s = bs & 7;
    int tid = threadIdx.x;
    const u64* src = cand_ws + (size_t)b * SUBS * SUBCAP;
    for (int t = tid; t < SUBS * SUBCAP; t += 512) lists[t] = src[t];
    __syncthreads();
    u64 key = lists[(s << 9) + tid];
    if (key) {
        int lo[SUBS];
#pragma unroll
        for (int l = 0; l < SUBS; ++l) lo[l] = 0;
#pragma unroll
        for (int w2 = SUBCAP; w2 >= 1; w2 >>= 1) {   // 10 rounds
#pragma unroll
            for (int l = 0; l < SUBS; ++l) {
                int p = lo[l] + w2;
                if (p <= SUBCAP && lists[(l << 9) + p - 1] > key) lo[l] = p;
            }
        }
        int rank = 0;
#pragma unroll
        for (int l = 0; l < SUBS; ++l) rank += lo[l];
        if (rank < TOPK) {
            u32 r = ~(u32)key;
            const float* p = pred + ((size_t)b * NPRED + r) * ROWF;
            float x = p[0], y = p[1], wd = p[2], hh = p[3];
            float4 box = make_float4(x - wd * 0.5f, y - hh * 0.5f,
                                     x + wd * 0.5f, y + hh * 0.5f);
            float4 sa = make_float4(__uint_as_float((u32)(key >> 32)),
                                    p[6], p[7], p[8]);
            bx_ws[(size_t)b * TKROW + rank] = box;
            sa_ws[(size_t)b * TKROW + rank] = sa;
        }
    }
}

// K3: suppression matrix as 136 upper-triangle 64x64 tiles per image,
// one tile per wave (8 blocks/image x 16 waves). Boxes read coalesced from
// bx_ws; area recomputed in-register (identical expression). j is
// wave-uniform -> LDS broadcast reads; word accumulates in a register.
__global__ __launch_bounds__(1024) void supmat_kernel(const float4* __restrict__ bx_ws,
                                                      u64* __restrict__ sup_g) {
    __shared__ float4 bx_s[1024];   // 16 KB
    __shared__ float  ar_s[1024];   // 4 KB
    int b = blockIdx.x >> 3, q = blockIdx.x & 7;
    int tid = threadIdx.x;
    {
        float4 box = bx_ws[(size_t)b * TKROW + tid];  // slots>=TOPK zeroed in K1
        bx_s[tid] = box;
        ar_s[tid] = (box.z - box.x) * (box.w - box.y); // zero box -> ar 0 -> iou 0
    }
    __syncthreads();
    int wave = tid >> 6, lane = tid & 63;
    for (int pass = 0; pass < 2; ++pass) {
        int t = (pass == 0) ? (q * 16 + wave) : ((wave == 15) ? 128 + q : 136);
        if (t >= 136) continue;
        // decode tile t -> (iw, jw), jw >= iw
        int iw = 0, rem = t, c = 16;
        while (rem >= c) { rem -= c; c--; iw++; }
        int jw = iw + rem;
        int i = iw * 64 + lane;
        bool act = i < TOPK;
        float4 bi = act ? bx_s[i] : make_float4(0.f, 0.f, 0.f, 0.f);
        float ai = act ? ar_s[i] : 0.f;
        u64 m = 0;
        int jbase = jw << 6;
        int jend = jbase + 64; if (jend > TOPK) jend = TOPK;
        for (int j = jbase; j < jend; ++j) {
            float4 bj = bx_s[j];            // broadcast
            float aj = ar_s[j];             // broadcast
            float lx = fmaxf(bi.x, bj.x);
            float ly = fmaxf(bi.y, bj.y);
            float rx = fminf(bi.z, bj.z);
            float ry = fminf(bi.w, bj.w);
            float iw2 = rx - lx; iw2 = iw2 > 0.f ? iw2 : 0.f;
            float ih = ry - ly; ih = ih > 0.f ? ih : 0.f;
            float inter = iw2 * ih;
            float den = ai + aj - inter + 1e-7f;  // ((ai+aj)-inter)+eps, ref order
            float iou = inter / den;
            if (act && j > i && iou > IOU_T) m |= 1ull << (j - jbase);
        }
        if (act) sup_g[((size_t)b * KW + jw) * SUPROW + i] = m;
    }
}

// K4: sparse register-resident greedy scan + output, all inputs coalesced SoA.
// keep0 from score!=0 via ballot. Serial loop only visits rows that actually
// suppress (ballot-gated); uniform broadcasts via v_readlane (VALU pipe).
__global__ __launch_bounds__(1024) void scan_out_kernel(const float4* __restrict__ bx_ws,
                                                        const float4* __restrict__ sa_ws,
                                                        const u64* __restrict__ sup_g,
                                                        float* __restrict__ out,
                                                        float* __restrict__ keepout) {
    __shared__ u64 keep_lds[KW];
    __shared__ u64 acc_lds;
    int b = blockIdx.x, tid = threadIdx.x;
    int w = tid >> 6, lane = tid & 63;
    const u64* S = sup_g + (size_t)b * KW * SUPROW;

    float4 sa = sa_ws[(size_t)b * TKROW + tid];   // slots >= TOPK are zero
    u64 keep0 = __ballot(sa.x != 0.f);            // row w*64+lane occupied
    if (lane == 0) keep_lds[w] = keep0;

    u64 sup_reg[KW];
    u64 diagreg = 0;
#pragma unroll
    for (int bi = 0; bi < KW; ++bi) {
        sup_reg[bi] = S[(size_t)w * SUPROW + (bi << 6) + lane]; // bi>w: garbage, never used
        if (bi == w) diagreg = sup_reg[bi];
    }
    __syncthreads();

    u64 nzmask = __ballot(diagreg != 0);   // rows of this word with in-word suppression

#pragma unroll
    for (int bi = 0; bi < KW; ++bi) {
        if (w == bi) {
            // serial greedy within word bi; only suppressor rows enter the loop
            u64 cur = keep_lds[bi];
            u64 active = cur & nzmask;
            while (active) {
                int i = __ffsll((long long)active) - 1;
                u64 wi = readlane64(diagreg, i);   // row i's mask (bits > i only)
                active &= active - 1;              // retire bit i
                cur &= ~wi;
                active &= ~wi;                     // suppressed rows can't suppress
            }
            if (lane == 0) { keep_lds[bi] = cur; acc_lds = cur; }
        }
        __syncthreads();
        if (w > bi) {
            u64 A = acc_lds;                       // accepted set of block bi
            u64 myv = sup_reg[bi];                 // row (bi*64+lane)'s mask over word w
            bool accb = (A >> lane) & 1ull;
            u64 lanes = __ballot(accb && myv != 0ull);
            if (lanes) {                           // rare: sparse suppression
                u64 wred = 0;
                while (lanes) {
                    int l = __ffsll((long long)lanes) - 1;
                    wred |= readlane64(myv, l);
                    lanes &= lanes - 1;
                }
                if (lane == 0) keep_lds[w] &= ~wred;
            }
        }
        __syncthreads();
    }

    if (tid < TOPK) {
        bool kp = ((keep_lds[w] >> lane) & 1ull) != 0;
        float4 bx = bx_ws[(size_t)b * TKROW + tid];  // coalesced
        size_t ob = ((size_t)b * TOPK + tid) * ROWF;
        out[ob + 0] = kp ? bx.x : 0.f;
        out[ob + 1] = kp ? bx.y : 0.f;
        out[ob + 2] = kp ? bx.z : 0.f;
        out[ob + 3] = kp ? bx.w : 0.f;
        out[ob + 4] = kp ? sa.x : 0.f;
        out[ob + 5] = 0.f;
        out[ob + 6] = kp ? sa.y : 0.f;
        out[ob + 7] = kp ? sa.z : 0.f;
        out[ob + 8] = kp ? sa.w : 0.f;
        keepout[(size_t)b * TOPK + tid] = kp ? 1.0f : 0.0f;
    }
}

extern "C" void kernel_launch(void* const* d_in, const int* in_sizes, int n_in,
                              void* d_out, int out_size, void* d_ws, size_t ws_size,
                              hipStream_t stream) {
    const float* pred = (const float*)d_in[0];
    float* out = (float*)d_out;                         // [32,1000,9]
    float* keepout = out + (size_t)BATCH * TOPK * ROWF; // [32,1000]
    char* ws = (char*)d_ws;
    u64* cand_ws = (u64*)(ws + WS_CAND);
    float4* bx_ws = (float4*)(ws + WS_BX);
    float4* sa_ws = (float4*)(ws + WS_SA);
    u64* sup_g = (u64*)(ws + WS_SUP);

    compact_sort_kernel<<<BATCH * SUBS, 512, 0, stream>>>(pred, cand_ws, bx_ws, sa_ws);
    rank_kernel<<<BATCH * SUBS, 512, 0, stream>>>(pred, cand_ws, bx_ws, sa_ws);
    supmat_kernel<<<BATCH * SUBS, 1024, 0, stream>>>(bx_ws, sup_g);
    scan_out_kernel<<<BATCH, 1024, 0, stream>>>(bx_ws, sa_ws, sup_g, out, keepout);
}

// Round 13
// 124.029 us; speedup vs baseline: 1.8235x; 1.0041x over previous
//
#include <hip/hip_runtime.h>
#include <stdint.h>

// Match reference numerics: no FMA contraction anywhere (discrete IoU>thres
// decisions flip on 1-ulp differences).
#pragma clang fp contract(off)

#define BATCH 32
#define NPRED 25200
#define ROWF 9
#define TOPK 1000
#define SUBS 8
#define ROWS_PER_SUB (NPRED / SUBS)   // 3150
#define SUBCAP 512
#define CONF_T 0.7f
#define IOU_T 0.45f
#define KW 16          // 1000 bits -> 16 u64 words
#define SUPROW 1024    // global sup stride per word-column
#define TKROW 1024     // bx/sa stride per image

typedef unsigned long long u64;
typedef unsigned int u32;

// ---- workspace layout (bytes) ----
#define WS_CAND 0                      // 256 lists x 512 u64 = 1,048,576
#define WS_BX   (1048576)              // 32 x 1024 float4    =   524,288
#define WS_SA   (WS_BX + 524288)       // 32 x 1024 float4    =   524,288
#define WS_SUP  (WS_SA + 524288)       // 32 x 16 x 1024 u64  = 4,194,304

// Session notes baked in:
//  - R8: grid-wide cooperative grid.sync ~60+ us/sync. Never.
//  - R11: per-image device-scope flag barriers stall ~145 us total (agent
//    fences cross the per-XCD L2). Launch boundaries are the cheapest sync.
//  - R9: LDS-broadcast loops concentrated on few CUs serialize on the per-CU
//    LDS pipe -> R13 moves K3 broadcasts to v_readlane (VALU) entirely.
//  - R12: top-1000 rows gathered ONCE (rank kernel), SoA after that.

__device__ __forceinline__ u64 readlane64(u64 v, int l) {
    // wave-uniform lane index -> v_readlane_b32 x2 (VALU, no LDS pipe)
    u32 lo = __builtin_amdgcn_readlane((u32)v, (u32)l);
    u32 hi = __builtin_amdgcn_readlane((u32)(v >> 32), (u32)l);
    return ((u64)hi << 32) | lo;
}
__device__ __forceinline__ float readlanef(float v, int l) {
    return __uint_as_float(__builtin_amdgcn_readlane(__float_as_uint(v), (u32)l));
}
__device__ __forceinline__ u64 shflxor64(u64 v, int m) {
    u32 lo = __shfl_xor((u32)v, m, 64);
    u32 hi = __shfl_xor((u32)(v >> 32), m, 64);
    return ((u64)hi << 32) | lo;
}

// K1: compact valid rows of one (image, sub-range) into keys, then bitonic-sort
// 512 keys (descending; zeros pad the tail). key = (float_bits(conf)<<32) | ~row
// -> desc order == (score desc, idx asc), exactly jax.lax.top_k tie-breaking.
// ~317 valid rows per 3150 expected; SUBCAP=512 is mean+11.5 sigma.
// Hybrid bitonic (R13): one key per thread in a register; the 39 passes with
// j<=32 exchange via __shfl_xor (no LDS, no barrier); only the 6 cross-wave
// passes (j>=64) round-trip LDS. Also zeroes bx/sa slices (0xAA-poisoned).
__global__ __launch_bounds__(512) void compact_sort_kernel(const float* __restrict__ pred,
                                                           u64* __restrict__ cand_ws,
                                                           float4* __restrict__ bx_ws,
                                                           float4* __restrict__ sa_ws) {
    __shared__ u64 skey[SUBCAP];          // 4096 B
    __shared__ u32 cnt;
    int bs = blockIdx.x;          // 0..255
    int b = bs >> 3, s = bs & 7;
    int tid = threadIdx.x;
    if (tid == 0) cnt = 0;
    skey[tid] = 0;
    if (tid < 128) {
        float4 z = make_float4(0.f, 0.f, 0.f, 0.f);
        bx_ws[(size_t)b * TKROW + s * 128 + tid] = z;
        sa_ws[(size_t)b * TKROW + s * 128 + tid] = z;
    }
    __syncthreads();

    // gather cols 4,5 for my rows: r = r0 + tid + k*512, k=0..6 (3150 = 6*512+78)
    int r0 = s * ROWS_PER_SUB;
    const int NCH = (ROWS_PER_SUB + 511) / 512;   // 7
    float objv[NCH], clsv[NCH];
#pragma unroll
    for (int k = 0; k < NCH; ++k) {
        int r = tid + k * 512;
        if (r < ROWS_PER_SUB) {
            size_t base = ((size_t)b * NPRED + r0 + r) * ROWF;
            objv[k] = pred[base + 4];
            clsv[k] = pred[base + 5];
        }
    }
#pragma unroll
    for (int k = 0; k < NCH; ++k) {
        int r = tid + k * 512;
        if (r < ROWS_PER_SUB) {
            float conf = objv[k] * clsv[k];
            if (objv[k] > CONF_T && conf > CONF_T) {
                int row = r0 + r;
                u32 slot = atomicAdd(&cnt, 1u);
                if (slot < SUBCAP)
                    skey[slot] = ((u64)__float_as_uint(conf) << 32) | (u64)(u32)(~(u32)row);
            }
        }
    }
    __syncthreads();

    // hybrid bitonic sort, descending, 512 elements, one key/thread
    u64 key = skey[tid];
    bool wrote = true;   // skey currently matches registers
    for (int k = 2; k <= SUBCAP; k <<= 1) {
        for (int j = k >> 1; j > 0; j >>= 1) {
            bool desc = ((tid & k) == 0);
            bool up = ((tid & j) == 0);     // I'm the lower index of the pair
            u64 part;
            if (j >= 64) {
                if (!wrote) { __syncthreads(); skey[tid] = key; }
                __syncthreads();
                part = skey[tid ^ j];
                wrote = false;              // registers will diverge from skey
            } else {
                part = shflxor64(key, j);
                wrote = false;
            }
            bool takemax = (desc == up);    // desc: lower holds larger
            u64 mx = key > part ? key : part;
            u64 mn = key > part ? part : key;
            key = takemax ? mx : mn;
        }
    }
    cand_ws[(size_t)bs * SUBCAP + tid] = key;
}

// K2: rank + gather + publish SoA. 8 blocks per image; each block ranks its
// own sub-list's 512 keys (rank = sum over all 8 sorted lists of count(>key);
// keys unique -> ranks exact/unique). For rank < TOPK, gather the pred row
// ONCE, compute the box (identical FP expressions), and scatter
// bx_ws[b][rank] = (x1,y1,x2,y2), sa_ws[b][rank] = (score,p6,p7,p8).
__global__ __launch_bounds__(512) void rank_kernel(const float* __restrict__ pred,
                                                   const u64* __restrict__ cand_ws,
                                                   float4* __restrict__ bx_ws,
                                                   float4* __restrict__ sa_ws) {
    __shared__ u64 lists[SUBS * SUBCAP];   // 32 KB
    int bs = blockIdx.x;          // 0..255
    int b = bs >> 3, s = bs & 7;
    int tid = threadIdx.x;
    const u64* src = cand_ws + (size_t)b * SUBS * SUBCAP;
    for (int t = tid; t < SUBS * SUBCAP; t += 512) lists[t] = src[t];
    __syncthreads();
    u64 key = lists[(s << 9) + tid];
    if (key) {
        int lo[SUBS];
#pragma unroll
        for (int l = 0; l < SUBS; ++l) lo[l] = 0;
#pragma unroll
        for (int w2 = SUBCAP; w2 >= 1; w2 >>= 1) {   // 10 rounds
#pragma unroll
            for (int l = 0; l < SUBS; ++l) {
                int p = lo[l] + w2;
                if (p <= SUBCAP && lists[(l << 9) + p - 1] > key) lo[l] = p;
            }
        }
        int rank = 0;
#pragma unroll
        for (int l = 0; l < SUBS; ++l) rank += lo[l];
        if (rank < TOPK) {
            u32 r = ~(u32)key;
            const float* p = pred + ((size_t)b * NPRED + r) * ROWF;
            float x = p[0], y = p[1], wd = p[2], hh = p[3];
            float4 box = make_float4(x - wd * 0.5f, y - hh * 0.5f,
                                     x + wd * 0.5f, y + hh * 0.5f);
            float4 sa = make_float4(__uint_as_float((u32)(key >> 32)),
                                    p[6], p[7], p[8]);
            bx_ws[(size_t)b * TKROW + rank] = box;
            sa_ws[(size_t)b * TKROW + rank] = sa;
        }
    }
}

// K3: suppression matrix as 136 upper-triangle 64x64 tiles per image,
// one tile per wave (8 blocks/image x 16 waves). R13: j-tile rows live in
// lane registers; per-j broadcast via v_readlane (VALU) -- 2 LDS reads per
// tile instead of 128 (R9 lesson: per-CU LDS pipe is the scarce resource).
__global__ __launch_bounds__(1024) void supmat_kernel(const float4* __restrict__ bx_ws,
                                                      u64* __restrict__ sup_g) {
    __shared__ float4 bx_s[1024];   // 16 KB
    __shared__ float  ar_s[1024];   // 4 KB
    int b = blockIdx.x >> 3, q = blockIdx.x & 7;
    int tid = threadIdx.x;
    {
        float4 box = bx_ws[(size_t)b * TKROW + tid];  // slots>=TOPK zeroed in K1
        bx_s[tid] = box;
        ar_s[tid] = (box.z - box.x) * (box.w - box.y); // zero box -> ar 0 -> iou 0
    }
    __syncthreads();
    int wave = tid >> 6, lane = tid & 63;
    for (int pass = 0; pass < 2; ++pass) {
        int t = (pass == 0) ? (q * 16 + wave) : ((wave == 15) ? 128 + q : 136);
        if (t >= 136) continue;
        // decode tile t -> (iw, jw), jw >= iw
        int iw = 0, rem = t, c = 16;
        while (rem >= c) { rem -= c; c--; iw++; }
        int jw = iw + rem;
        int i = iw * 64 + lane;
        bool act = i < TOPK;
        float4 bi4 = bx_s[i];
        float ai = ar_s[i];
        float4 bja = bx_s[(jw << 6) + lane];    // this lane's j-row
        float aja = ar_s[(jw << 6) + lane];
        u64 m = 0;
        int jbase = jw << 6;
        for (int l2 = 0; l2 < 64; ++l2) {
            float bjx = readlanef(bja.x, l2);
            float bjy = readlanef(bja.y, l2);
            float bjz = readlanef(bja.z, l2);
            float bjw = readlanef(bja.w, l2);
            float aj  = readlanef(aja, l2);
            float lx = fmaxf(bi4.x, bjx);
            float ly = fmaxf(bi4.y, bjy);
            float rx = fminf(bi4.z, bjz);
            float ry = fminf(bi4.w, bjw);
            float iw2 = rx - lx; iw2 = iw2 > 0.f ? iw2 : 0.f;
            float ih = ry - ly; ih = ih > 0.f ? ih : 0.f;
            float inter = iw2 * ih;
            float den = ai + aj - inter + 1e-7f;  // ((ai+aj)-inter)+eps, ref order
            float iou = inter / den;
            if (act && (jbase + l2) > i && iou > IOU_T) m |= 1ull << l2;
        }
        if (act) sup_g[((size_t)b * KW + jw) * SUPROW + i] = m;
    }
}

// K4: sparse register-resident greedy scan + output, all inputs coalesced SoA.
// keep0 from score!=0 via ballot. Serial loop only visits rows that actually
// suppress (ballot-gated); uniform broadcasts via v_readlane (VALU pipe).
// R13: preload gated to bi<=w (wave-uniform) -- halves the sup_g traffic.
__global__ __launch_bounds__(1024) void scan_out_kernel(const float4* __restrict__ bx_ws,
                                                        const float4* __restrict__ sa_ws,
                                                        const u64* __restrict__ sup_g,
                                                        float* __restrict__ out,
                                                        float* __restrict__ keepout) {
    __shared__ u64 keep_lds[KW];
    __shared__ u64 acc_lds;
    int b = blockIdx.x, tid = threadIdx.x;
    int w = tid >> 6, lane = tid & 63;
    const u64* S = sup_g + (size_t)b * KW * SUPROW;

    float4 sa = sa_ws[(size_t)b * TKROW + tid];   // slots >= TOPK are zero
    u64 keep0 = __ballot(sa.x != 0.f);            // row w*64+lane occupied
    if (lane == 0) keep_lds[w] = keep0;

    u64 sup_reg[KW];
    u64 diagreg = 0;
#pragma unroll
    for (int bi = 0; bi < KW; ++bi) {
        sup_reg[bi] = 0;
        if (bi <= w)    // wave-uniform; bi>w never used
            sup_reg[bi] = S[(size_t)w * SUPROW + (bi << 6) + lane];
        if (bi == w) diagreg = sup_reg[bi];
    }
    __syncthreads();

    u64 nzmask = __ballot(diagreg != 0);   // rows of this word with in-word suppression

#pragma unroll
    for (int bi = 0; bi < KW; ++bi) {
        if (w == bi) {
            // serial greedy within word bi; only suppressor rows enter the loop
            u64 cur = keep_lds[bi];
            u64 active = cur & nzmask;
            while (active) {
                int i = __ffsll((long long)active) - 1;
                u64 wi = readlane64(diagreg, i);   // row i's mask (bits > i only)
                active &= active - 1;              // retire bit i
                cur &= ~wi;
                active &= ~wi;                     // suppressed rows can't suppress
            }
            if (lane == 0) { keep_lds[bi] = cur; acc_lds = cur; }
        }
        __syncthreads();
        if (w > bi) {
            u64 A = acc_lds;                       // accepted set of block bi
            u64 myv = sup_reg[bi];                 // row (bi*64+lane)'s mask over word w
            bool accb = (A >> lane) & 1ull;
            u64 lanes = __ballot(accb && myv != 0ull);
            if (lanes) {                           // rare: sparse suppression
                u64 wred = 0;
                while (lanes) {
                    int l = __ffsll((long long)lanes) - 1;
                    wred |= readlane64(myv, l);
                    lanes &= lanes - 1;
                }
                if (lane == 0) keep_lds[w] &= ~wred;
            }
        }
        __syncthreads();
    }

    if (tid < TOPK) {
        bool kp = ((keep_lds[w] >> lane) & 1ull) != 0;
        float4 bx = bx_ws[(size_t)b * TKROW + tid];  // coalesced
        size_t ob = ((size_t)b * TOPK + tid) * ROWF;
        out[ob + 0] = kp ? bx.x : 0.f;
        out[ob + 1] = kp ? bx.y : 0.f;
        out[ob + 2] = kp ? bx.z : 0.f;
        out[ob + 3] = kp ? bx.w : 0.f;
        out[ob + 4] = kp ? sa.x : 0.f;
        out[ob + 5] = 0.f;
        out[ob + 6] = kp ? sa.y : 0.f;
        out[ob + 7] = kp ? sa.z : 0.f;
        out[ob + 8] = kp ? sa.w : 0.f;
        keepout[(size_t)b * TOPK + tid] = kp ? 1.0f : 0.0f;
    }
}

extern "C" void kernel_launch(void* const* d_in, const int* in_sizes, int n_in,
                              void* d_out, int out_size, void* d_ws, size_t ws_size,
                              hipStream_t stream) {
    const float* pred = (const float*)d_in[0];
    float* out = (float*)d_out;                         // [32,1000,9]
    float* keepout = out + (size_t)BATCH * TOPK * ROWF; // [32,1000]
    char* ws = (char*)d_ws;
    u64* cand_ws = (u64*)(ws + WS_CAND);
    float4* bx_ws = (float4*)(ws + WS_BX);
    float4* sa_ws = (float4*)(ws + WS_SA);
    u64* sup_g = (u64*)(ws + WS_SUP);

    compact_sort_kernel<<<BATCH * SUBS, 512, 0, stream>>>(pred, cand_ws, bx_ws, sa_ws);
    rank_kernel<<<BATCH * SUBS, 512, 0, stream>>>(pred, cand_ws, bx_ws, sa_ws);
    supmat_kernel<<<BATCH * SUBS, 1024, 0, stream>>>(bx_ws, sup_g);
    scan_out_kernel<<<BATCH, 1024, 0, stream>>>(bx_ws, sa_ws, sup_g, out, keepout);
}